// Round 1
// baseline (819.410 us; speedup 1.0000x reference)
//
#include <hip/hip_runtime.h>
#include <math.h>

// Turb2dPDE: per batch b (4096):
//   psi = Re(IDFT2( S_env ∘ DFT2(pad65(-x)) ))[:64,:64]   (65x65 spectral Poisson)
//   dudt = -(J1+J2+J3)/(12*fdx^2) + mu*lap/fdx^2          (Arakawa + laplacian stencils)
// DFT2 done as small dense matmuls from precomputed trig tables, Hermitian-halved:
//   forward rows j=0..32 only; half-inverse X columns c=0..32 only (X[:,65-c]=conj(X[:,c])).
// One block (256 thr) per batch item, all intermediates in 51.2 KB LDS.

#define NP1 65

// table offsets (floats) in d_ws
#define OFF_CF   0      // Cf,Sf: folded forward DFT rows  [33][64]
#define OFF_SF   2112
#define OFF_C2   4224   // C2,S2: folded right-DFT          [64][65]
#define OFF_S2   8384
#define OFF_GRT  12544  // Grt,Git: inverse (transposed)    [33][64]  Grt[j][r]=cos(w*r*j)
#define OFF_GIT  14656
#define OFF_HC   16768  // Hc,Hs: final half-inverse        [33][64]  (incl 1/4225, x2 for c>=1)
#define OFF_HS   18880
#define OFF_SE   20992  // Senv: -1/(1e-12+k2)              [8][33][33]
#define TBL_FLOATS 29704

__global__ void setup_tables(float* __restrict__ tbl, const float* __restrict__ domain) {
    const int idx = blockIdx.x * 256 + threadIdx.x;
    const float w = 6.283185307179586f / 65.0f;
    const float DX0 = 0.04908738521234052f; // pi/64
    if (idx < 2112) {                       // Cf,Sf : j 0..32, m 0..63 (m==0 folds m=64 row)
        int j = idx >> 6, m = idx & 63;
        int t = (j * m) % 65;
        float c = cosf(w * (float)t), s = sinf(w * (float)t);
        if (m == 0) { int t2 = (j * 64) % 65; c += cosf(w * (float)t2); s += sinf(w * (float)t2); }
        tbl[OFF_CF + idx] = c; tbl[OFF_SF + idx] = s;
    } else if (idx < 6272) {                // C2,S2 : k 0..63, c 0..64 (k==0 folds k=64)
        int r = idx - 2112; int k = (unsigned)r / 65u; int c = r - k * 65;
        int t = (k * c) % 65;
        float cv = cosf(w * (float)t), sv = sinf(w * (float)t);
        if (k == 0) { int t2 = (64 * c) % 65; cv += cosf(w * (float)t2); sv += sinf(w * (float)t2); }
        tbl[OFF_C2 + r] = cv; tbl[OFF_S2 + r] = sv;
    } else if (idx < 8384) {                // Grt,Git : j 0..32, r 0..63
        int r0 = idx - 6272; int j = r0 >> 6, rr = r0 & 63;
        int t = (j * rr) % 65;
        tbl[OFF_GRT + r0] = cosf(w * (float)t);
        tbl[OFF_GIT + r0] = sinf(w * (float)t);
    } else if (idx < 10496) {               // Hc,Hs : c 0..32, cp 0..63
        int r0 = idx - 8384; int c = r0 >> 6, cp = r0 & 63;
        const float inv = 1.0f / 4225.0f;
        if (c == 0) { tbl[OFF_HC + r0] = inv; tbl[OFF_HS + r0] = 0.0f; }
        else {
            int t = (c * cp) % 65;
            tbl[OFF_HC + r0] = 2.0f * inv * cosf(w * (float)t);
            tbl[OFF_HS + r0] = 2.0f * inv * sinf(w * (float)t);
        }
    } else if (idx < 19208) {               // Senv : e 0..7, j 0..32, cc 0..32
        int r0 = idx - 10496;
        int e = (unsigned)r0 / 1089u; int rem = r0 - e * 1089;
        int j = (unsigned)rem / 33u;  int cc = rem - j * 33;
        float fdx = domain[e] * DX0;
        float tt = 6.283185307179586f / (65.0f * fdx);
        float s2 = tt * tt;
        tbl[OFF_SE + r0] = -1.0f / (1e-12f + s2 * (float)(j * j + cc * cc));
    }
}

__global__ __launch_bounds__(256)
void turb_kernel(const float* __restrict__ y0, const int* __restrict__ env,
                 const float* __restrict__ params, const float* __restrict__ domain,
                 const float* __restrict__ tbl, float* __restrict__ out) {
    // LDS arenas (floats): xb[64][65] | arena2: P,Q[33][64] then Xr,Xi[64][33] | arena3: Ur,Ui[33][65] then psi[64][65]
    __shared__ float lds[12802];
    float* xb = lds;                    // 4160
    float* P  = lds + 4160;             // 2112
    float* Q  = lds + 4160 + 2112;      // 2112
    float* Xr = lds + 4160;             // reuse of P/Q arena
    float* Xi = lds + 4160 + 2112;
    float* Ur = lds + 8512;             // 2145
    float* Ui = lds + 8512 + 2145;      // 2145
    float* psi = lds + 8512;            // 4160, reuse of U arena

    const int b = blockIdx.x;
    const int tid = threadIdx.x;
    const int e = env[b];
    const float mu = params[2 * e];
    const float DX0 = 0.04908738521234052f;
    const float fdx = domain[e] * DX0;
    const float fdx2 = fdx * fdx;

    const float* Cf  = tbl + OFF_CF;
    const float* Sf  = tbl + OFF_SF;
    const float* C2  = tbl + OFF_C2;
    const float* S2  = tbl + OFF_S2;
    const float* Grt = tbl + OFF_GRT;
    const float* Git = tbl + OFF_GIT;
    const float* Hc  = tbl + OFF_HC;
    const float* Hs  = tbl + OFF_HS;
    const float* Se  = tbl + OFF_SE + e * 1089;

    // load x (64x64) into padded-stride LDS
    const float* x0 = y0 + (size_t)b * 4096;
    for (int i = tid; i < 4096; i += 256)
        xb[(i >> 6) * NP1 + (i & 63)] = x0[i];
    __syncthreads();

    // step1: T = F * pad(-x), rows j=0..32, cols k=0..63 (col 64 folded away downstream)
    for (int i = tid; i < 2112; i += 256) {
        int j = i >> 6, k = i & 63;
        float ar = 0.0f, ai = 0.0f;
        const float* cf = Cf + j * 64;
        const float* sf = Sf + j * 64;
        #pragma unroll 8
        for (int m = 0; m < 64; m++) {
            float xv = xb[m * NP1 + k];
            ar -= cf[m] * xv;   // Tr = sum cos * (-x)
            ai += sf[m] * xv;   // Ti = -sum sin * (-x)
        }
        P[i] = ar; Q[i] = ai;
    }
    __syncthreads();

    // step2+3: W = T * F2 (cols 0..64), then U = S .* W, U[0][0]=0
    for (int i = tid; i < 2145; i += 256) {
        int j = (unsigned)i / 65u; int c = i - j * 65;
        float wr = 0.0f, wi = 0.0f;
        const float* pr = P + j * 64;
        const float* qr = Q + j * 64;
        #pragma unroll 8
        for (int k = 0; k < 64; k++) {
            float p = pr[k], q = qr[k];
            float c2 = C2[k * 65 + c], s2 = S2[k * 65 + c];
            wr += p * c2 + q * s2;
            wi += q * c2 - p * s2;
        }
        int cc = (c <= 32) ? c : 65 - c;
        float s = Se[j * 33 + cc];
        float ur = s * wr, ui = s * wi;
        if (i == 0) { ur = 0.0f; ui = 0.0f; }   // (j,c)=(0,0)
        Ur[i] = ur; Ui[i] = ui;                 // i == j*65+c
    }
    __syncthreads();

    // pair transform (in place): col c := U[:,c]+U[:,65-c], col 65-c := U[:,c]-U[:,65-c]
    // row j=0: col 65-c := col c copy. col 0: rows j>=1 *= 2.
    for (int i = tid; i < 1089; i += 256) {
        int c = (unsigned)i / 33u; int j = i - c * 33;
        if (c == 0) {
            if (j > 0) { Ur[j * 65] *= 2.0f; Ui[j * 65] *= 2.0f; }
        } else {
            int cm = 65 - c;
            if (j == 0) { Ur[cm] = Ur[c]; Ui[cm] = Ui[c]; }
            else {
                int a = j * 65 + c, bb = j * 65 + cm;
                float u1 = Ur[a], u2 = Ur[bb]; Ur[a] = u1 + u2; Ur[bb] = u1 - u2;
                float v1 = Ui[a], v2 = Ui[bb]; Ui[a] = v1 + v2; Ui[bb] = v1 - v2;
            }
        }
    }
    __syncthreads();

    // step4a: X[r][c] c=0..32 (Xr from plus-combos at col c, Xi from minus-combos at col 65-c)
    for (int i = tid; i < 2112; i += 256) {
        int c = i >> 6, r = i & 63;
        int cm = (c == 0) ? 0 : 65 - c;
        float xr = 0.0f, xi = 0.0f;
        #pragma unroll 4
        for (int j = 0; j < 33; j++) {
            float gr = Grt[j * 64 + r], gi = Git[j * 64 + r];
            float upr = Ur[j * 65 + c],  upi = Ui[j * 65 + c];
            float umr = Ur[j * 65 + cm], umi = Ui[j * 65 + cm];
            xr += gr * upr - gi * upi;
            xi += gr * umi + gi * umr;
        }
        if (c == 0) xi = 0.0f;
        Xr[r * 33 + c] = xr; Xi[r * 33 + c] = xi;
    }
    __syncthreads();

    // step4b: psi[r][cp] = sum_c Xr*Hc - Xi*Hs   (Hc/Hs carry 1/4225 and the x2 pairing)
    for (int i = tid; i < 4096; i += 256) {
        int r = i >> 6, cp = i & 63;
        float acc = 0.0f;
        #pragma unroll 4
        for (int c = 0; c < 33; c++)
            acc += Xr[r * 33 + c] * Hc[c * 64 + cp] - Xi[r * 33 + c] * Hs[c * 64 + cp];
        psi[r * NP1 + cp] = acc;
    }
    __syncthreads();

    // step5: stencils (periodic mod 64)
    float* o = out + (size_t)b * 4096;
    const float inv4 = 1.0f / (4.0f * fdx2);
    const float invf = 1.0f / fdx2;
    for (int i = tid; i < 4096; i += 256) {
        int r = i >> 6, c = i & 63;
        int rp = (r + 1) & 63, rm = (r - 1) & 63, cp = (c + 1) & 63, cm = (c - 1) & 63;
        float x_cc  = xb[r * NP1 + c];
        float x_rpc = xb[rp * NP1 + c],  x_rmc = xb[rm * NP1 + c];
        float x_rcp = xb[r * NP1 + cp],  x_rcm = xb[r * NP1 + cm];
        float x_rpcp = xb[rp * NP1 + cp], x_rpcm = xb[rp * NP1 + cm];
        float x_rmcp = xb[rm * NP1 + cp], x_rmcm = xb[rm * NP1 + cm];
        float p_rpc = psi[rp * NP1 + c],  p_rmc = psi[rm * NP1 + c];
        float p_rcp = psi[r * NP1 + cp],  p_rcm = psi[r * NP1 + cm];
        float p_rpcp = psi[rp * NP1 + cp], p_rpcm = psi[rp * NP1 + cm];
        float p_rmcp = psi[rm * NP1 + cp], p_rmcm = psi[rm * NP1 + cm];

        float J1 = (p_rpc - p_rmc) * (x_rcp - x_rcm) - (p_rcp - p_rcm) * (x_rpc - x_rmc);
        float J2 = x_rcp * (p_rpcp - p_rmcp) - x_rcm * (p_rpcm - p_rmcm)
                 - x_rpc * (p_rpcp - p_rpcm) + x_rmc * (p_rmcp - p_rmcm);
        float J3 = x_rpcp * (p_rpc - p_rcp) - x_rmcm * (p_rcm - p_rmc)
                 - x_rpcm * (p_rpc - p_rcm) + x_rmcp * (p_rcp - p_rmc);
        float lap = x_rmc + x_rcm - 4.0f * x_cc + x_rcp + x_rpcm + x_rpc;

        o[i] = -(J1 + J2 + J3) * inv4 * (1.0f / 3.0f) + mu * lap * invf;
    }
}

extern "C" void kernel_launch(void* const* d_in, const int* in_sizes, int n_in,
                              void* d_out, int out_size, void* d_ws, size_t ws_size,
                              hipStream_t stream) {
    // inputs: 0=t(1) 1=y0(B*64*64 f32) 2=env(B int) 3=codes(unused) 4=params(8x2 f32) 5=domain(8 f32)
    const float* y0     = (const float*)d_in[1];
    const int*   env    = (const int*)d_in[2];
    const float* params = (const float*)d_in[4];
    const float* domain = (const float*)d_in[5];
    float* out = (float*)d_out;
    float* tbl = (float*)d_ws;   // needs TBL_FLOATS*4 = 118.8 KB

    setup_tables<<<dim3(76), dim3(256), 0, stream>>>(tbl, domain);
    turb_kernel<<<dim3(4096), dim3(256), 0, stream>>>(y0, env, params, domain, tbl, out);
}

// Round 2
// 459.114 us; speedup vs baseline: 1.7848x; 1.7848x over previous
//
#include <hip/hip_runtime.h>
#include <math.h>

// Turb2dPDE: per batch b: psi = Re(IDFT2(S ∘ DFT2(pad65(-x))))[:64,:64], then Arakawa+laplacian.
// All transforms as register-blocked small matmuls; Hermitian + c/r/p symmetries halve steps 2/4a/4b.
// One 256-thread block per batch item; 51.98 KB LDS -> 3 blocks/CU.

#define THETA 0.09666439165562847f  // 2*pi/65

// table float-offsets in d_ws
#define OFF_F4   0        // [33j][32mp][4] {cf(2mp),sf(2mp),cf(2mp+1),sf(2mp+1)} (m=0 folds m=64)
#define OFF_CS4  4224     // [33c][32kp][4] {c2,s2,c2,s2} (k=0 folds k=64)
#define OFF_G4   8448     // [33s][16jp][4] {gr,gi,gr,gi}  gr=cos(th*j*s), gi=sin
#define OFF_GT   10560    // [33][2] tail j=32 (padded to 68)
#define OFF_H4   10628    // [33p][16cp][4] {hc,hs,hc,hs}  (1/4225, x2 for c>=1)
#define OFF_HT   12740    // [33][2] tail c=32 (padded to 68)
#define OFF_SE   12808    // [8][33][33]  -1/(1e-12+k2)  (symmetric in j,c)
#define TBL_FLOATS 21520

__global__ void setup_tables(float* __restrict__ tbl, const float* __restrict__ domain) {
    int idx = blockIdx.x * 256 + threadIdx.x;
    const float w = THETA;
    if (idx < 4224) {                       // F4
        int j = idx >> 7, rem = idx & 127, mp = rem >> 2, q = rem & 3;
        int m = 2 * mp + (q >> 1);
        int t = (j * m) % 65;
        float v = (q & 1) ? sinf(w * t) : cosf(w * t);
        if (m == 0) { int t2 = (j * 64) % 65; v += (q & 1) ? sinf(w * t2) : cosf(w * t2); }
        tbl[OFF_F4 + idx] = v;
    } else if (idx < 8448) {                // CS4
        int r0 = idx - 4224;
        int c = r0 >> 7, rem = r0 & 127, kp = rem >> 2, q = rem & 3;
        int k = 2 * kp + (q >> 1);
        int t = (k * c) % 65;
        float v = (q & 1) ? sinf(w * t) : cosf(w * t);
        if (k == 0) { int t2 = (64 * c) % 65; v += (q & 1) ? sinf(w * t2) : cosf(w * t2); }
        tbl[OFF_CS4 + r0] = v;
    } else if (idx < 10560) {               // G4
        int r0 = idx - 8448;
        int s = r0 >> 6, rem = r0 & 63, jp = rem >> 2, q = rem & 3;
        int j = 2 * jp + (q >> 1);
        int t = (j * s) % 65;
        tbl[OFF_G4 + r0] = (q & 1) ? sinf(w * t) : cosf(w * t);
    } else if (idx < 10628) {               // Gt
        int r0 = idx - 10560;
        int s = r0 >> 1;
        float v = 0.f;
        if (s < 33) { int t = (32 * s) % 65; v = (r0 & 1) ? sinf(w * t) : cosf(w * t); }
        tbl[OFF_GT + r0] = v;
    } else if (idx < 12740) {               // H4
        int r0 = idx - 10628;
        int p = r0 >> 6, rem = r0 & 63, cp = rem >> 2, q = rem & 3;
        int c = 2 * cp + (q >> 1);
        const float inv = 1.0f / 4225.0f;
        float v;
        if (c == 0) v = (q & 1) ? 0.f : inv;
        else { int t = (c * p) % 65; v = 2.f * inv * ((q & 1) ? sinf(w * t) : cosf(w * t)); }
        tbl[OFF_H4 + r0] = v;
    } else if (idx < 12808) {               // Ht
        int r0 = idx - 12740;
        int p = r0 >> 1;
        const float inv = 1.0f / 4225.0f;
        float v = 0.f;
        if (p < 33) { int t = (32 * p) % 65; v = 2.f * inv * ((r0 & 1) ? sinf(w * t) : cosf(w * t)); }
        tbl[OFF_HT + r0] = v;
    } else if (idx < TBL_FLOATS) {          // Se
        int r0 = idx - 12808;
        int e = r0 / 1089, rem = r0 - e * 1089;
        int a = rem / 33, b2 = rem - a * 33;
        const float DX0 = 0.04908738521234052f;
        float fdx = domain[e] * DX0;
        float tt = 6.283185307179586f / (65.0f * fdx);
        float s2 = tt * tt;
        tbl[OFF_SE + r0] = -1.0f / (1e-12f + s2 * (float)(a * a + b2 * b2));
    }
}

__global__ __launch_bounds__(256, 3)
void turb_kernel(const float* __restrict__ y0, const int* __restrict__ env,
                 const float* __restrict__ params, const float* __restrict__ domain,
                 const float* __restrict__ tbl, float* __restrict__ out) {
    // LDS: xbT[64c][65] | arenaB: P[33][66],Q[33][66] then XX[64r][35]float2 | arenaC: UU[33c][33j]float4 then psi[64][65]
    __shared__ float lds[12996];
    float*  xbT = lds;                        // 4160
    float*  P   = lds + 4160;                 // 2178
    float*  Q   = lds + 4160 + 2178;          // 2178
    float2* XX  = (float2*)(lds + 4160);      // 64*35 float2 = 4480 floats
    float4* UU  = (float4*)(lds + 8640);      // 33*33 float4 = 4356 floats
    float*  psi = lds + 8640;                 // 4160

    const int b = blockIdx.x, tid = threadIdx.x;
    const int lane = tid & 63, g = tid >> 6;
    const int e = env[b];

    // ---- load x into transposed LDS: xbT[c*65+r] = x[r][c]
    const float* x0 = y0 + (size_t)b * 4096;
    #pragma unroll
    for (int it = 0; it < 16; it++) {
        int i = tid + it * 256;
        int r = i >> 6, c = i & 63;
        xbT[c * 65 + r] = x0[i];
    }
    __syncthreads();

    // ---- step1: T = F * (-x): P=Tr,Q=Ti, rows j=0..32, lane=k
    {
        const int k = lane;
        float ar[9], ai[9];
        #pragma unroll
        for (int u = 0; u < 9; u++) { ar[u] = 0.f; ai[u] = 0.f; }
        const float4* F4 = (const float4*)(tbl + OFF_F4);
        for (int mp = 0; mp < 32; mp++) {
            float xA = xbT[k * 65 + 2 * mp];
            float xB = xbT[k * 65 + 2 * mp + 1];
            #pragma unroll
            for (int u = 0; u < 9; u++) {
                int j = (u == 8) ? 32 : (8 * g + u);
                float4 t = F4[j * 32 + mp];
                ar[u] -= t.x * xA; ai[u] += t.y * xA;
                ar[u] -= t.z * xB; ai[u] += t.w * xB;
            }
        }
        #pragma unroll
        for (int u = 0; u < 9; u++) {
            if (u < 8 || g == 3) {
                int j = (u == 8) ? 32 : (8 * g + u);
                P[j * 66 + k] = ar[u];
                Q[j * 66 + k] = ai[u];
            }
        }
    }
    __syncthreads();

    // ---- step2: A,B,C,D contractions over k; emit 4 streams UU[c][j]={upr,upi,umr,umi}, c=0..32
    if (lane < 33) {
        const int j = lane;
        float A[9], B[9], C[9], D[9];
        #pragma unroll
        for (int u = 0; u < 9; u++) { A[u] = 0.f; B[u] = 0.f; C[u] = 0.f; D[u] = 0.f; }
        const float4* CS4 = (const float4*)(tbl + OFF_CS4);
        for (int kp = 0; kp < 32; kp++) {
            float2 p2 = *(const float2*)&P[j * 66 + 2 * kp];
            float2 q2 = *(const float2*)&Q[j * 66 + 2 * kp];
            #pragma unroll
            for (int u = 0; u < 9; u++) {
                int c = (u == 8) ? 32 : (8 * g + u);
                float4 t = CS4[c * 32 + kp];
                A[u] += p2.x * t.x; B[u] += q2.x * t.x;
                C[u] += p2.x * t.y; D[u] += q2.x * t.y;
                A[u] += p2.y * t.z; B[u] += q2.y * t.z;
                C[u] += p2.y * t.w; D[u] += q2.y * t.w;
            }
        }
        const float* Se = tbl + OFF_SE + e * 1089;
        #pragma unroll
        for (int u = 0; u < 9; u++) {
            if (u < 8 || g == 3) {
                int c = (u == 8) ? 32 : (8 * g + u);
                float S = Se[c * 33 + j];
                float4 o;
                if (j == 0) {
                    float upr = S * (A[u] + D[u]), upi = S * (B[u] - C[u]);
                    if (c == 0) { upr = 0.f; upi = 0.f; }
                    o = make_float4(upr, upi, upr, upi);
                } else {
                    o = make_float4(2.f * S * A[u], 2.f * S * B[u], 2.f * S * D[u], -2.f * S * C[u]);
                }
                UU[c * 33 + j] = o;
            }
        }
    }
    __syncthreads();

    // ---- step4a: X[r][c] via r-symmetry: slot s emits rows s and 65-s. lane=c, contraction over j
    if (lane < 33) {
        const int c = lane;
        float a[9], bb[9], cc[9], dd[9];
        #pragma unroll
        for (int u = 0; u < 9; u++) { a[u] = 0.f; bb[u] = 0.f; cc[u] = 0.f; dd[u] = 0.f; }
        const float4* G4 = (const float4*)(tbl + OFF_G4);
        for (int jp = 0; jp < 16; jp++) {
            float4 u0 = UU[c * 33 + 2 * jp];
            float4 u1 = UU[c * 33 + 2 * jp + 1];
            #pragma unroll
            for (int u = 0; u < 9; u++) {
                int s = (u == 8) ? 32 : (8 * g + u);
                float4 t = G4[s * 16 + jp];
                a[u]  += t.x * u0.x; bb[u] += t.y * u0.y;
                cc[u] += t.x * u0.w; dd[u] += t.y * u0.z;
                a[u]  += t.z * u1.x; bb[u] += t.w * u1.y;
                cc[u] += t.z * u1.w; dd[u] += t.w * u1.z;
            }
        }
        {   // tail j=32
            float4 u0 = UU[c * 33 + 32];
            const float2* Gt = (const float2*)(tbl + OFF_GT);
            #pragma unroll
            for (int u = 0; u < 9; u++) {
                int s = (u == 8) ? 32 : (8 * g + u);
                float2 t = Gt[s];
                a[u]  += t.x * u0.x; bb[u] += t.y * u0.y;
                cc[u] += t.x * u0.w; dd[u] += t.y * u0.z;
            }
        }
        #pragma unroll
        for (int u = 0; u < 9; u++) {
            if (u < 8 || g == 3) {
                int s = (u == 8) ? 32 : (8 * g + u);
                XX[s * 35 + c] = make_float2(a[u] - bb[u], cc[u] + dd[u]);
                if (s >= 2) XX[(65 - s) * 35 + c] = make_float2(a[u] + bb[u], cc[u] - dd[u]);
            }
        }
    }
    __syncthreads();

    // ---- step4b: psi via p-symmetry: slot p emits cols p and 65-p. lane=r, contraction over c
    {
        const int r = lane;
        float E[9], F[9];
        #pragma unroll
        for (int u = 0; u < 9; u++) { E[u] = 0.f; F[u] = 0.f; }
        const float4* H4 = (const float4*)(tbl + OFF_H4);
        for (int cp = 0; cp < 16; cp++) {
            float2 xv0 = XX[r * 35 + 2 * cp];
            float2 xv1 = XX[r * 35 + 2 * cp + 1];
            #pragma unroll
            for (int u = 0; u < 9; u++) {
                int p = (u == 8) ? 32 : (8 * g + u);
                float4 t = H4[p * 16 + cp];
                E[u] += xv0.x * t.x; F[u] += xv0.y * t.y;
                E[u] += xv1.x * t.z; F[u] += xv1.y * t.w;
            }
        }
        {   // tail c=32
            float2 xv0 = XX[r * 35 + 32];
            const float2* Ht = (const float2*)(tbl + OFF_HT);
            #pragma unroll
            for (int u = 0; u < 9; u++) {
                int p = (u == 8) ? 32 : (8 * g + u);
                float2 t = Ht[p];
                E[u] += xv0.x * t.x; F[u] += xv0.y * t.y;
            }
        }
        #pragma unroll
        for (int u = 0; u < 9; u++) {
            if (u < 8 || g == 3) {
                int p = (u == 8) ? 32 : (8 * g + u);
                psi[r * 65 + p] = E[u] - F[u];
                if (p >= 2) psi[r * 65 + 65 - p] = E[u] + F[u];
            }
        }
    }
    __syncthreads();

    // ---- stencil: lane=c, rows 16g..16g+15, sliding 3x3 window
    {
        const int c = lane;
        const int cm1 = (c + 63) & 63, cp1 = (c + 1) & 63;
        const float mu = params[2 * e];
        const float DX0 = 0.04908738521234052f;
        const float fdx = domain[e] * DX0;
        const float fdx2 = fdx * fdx;
        const float inv12 = 1.0f / (12.0f * fdx2);
        const float invf = mu / fdx2;
        float* o = out + (size_t)b * 4096;
        const int r0 = g * 16;
        int rm = (r0 + 63) & 63;
        float xLm = xbT[cm1 * 65 + rm], xCm = xbT[c * 65 + rm], xRm = xbT[cp1 * 65 + rm];
        float pLm = psi[rm * 65 + cm1], pCm = psi[rm * 65 + c], pRm = psi[rm * 65 + cp1];
        float xLc = xbT[cm1 * 65 + r0], xCc = xbT[c * 65 + r0], xRc = xbT[cp1 * 65 + r0];
        float pLc = psi[r0 * 65 + cm1], pCc = psi[r0 * 65 + c], pRc = psi[r0 * 65 + cp1];
        #pragma unroll
        for (int it = 0; it < 16; it++) {
            int r = r0 + it;
            int rn = (r + 1) & 63;
            float xLp = xbT[cm1 * 65 + rn], xCp = xbT[c * 65 + rn], xRp = xbT[cp1 * 65 + rn];
            float pLp = psi[rn * 65 + cm1], pCp = psi[rn * 65 + c], pRp = psi[rn * 65 + cp1];
            float J1 = (pCp - pCm) * (xRc - xLc) - (pRc - pLc) * (xCp - xCm);
            float J2 = xRc * (pRp - pRm) - xLc * (pLp - pLm) - xCp * (pRp - pLp) + xCm * (pRm - pLm);
            float J3 = xRp * (pCp - pRc) - xLm * (pLc - pCm) - xLp * (pCp - pLc) + xRm * (pRc - pCm);
            float lap = xCm + xLc - 4.f * xCc + xRc + xLp + xCp;
            o[r * 64 + c] = -(J1 + J2 + J3) * inv12 + lap * invf;
            xLm = xLc; xCm = xCc; xRm = xRc; pLm = pLc; pCm = pCc; pRm = pRc;
            xLc = xLp; xCc = xCp; xRc = xRp; pLc = pLp; pCc = pCp; pRc = pRp;
        }
    }
}

extern "C" void kernel_launch(void* const* d_in, const int* in_sizes, int n_in,
                              void* d_out, int out_size, void* d_ws, size_t ws_size,
                              hipStream_t stream) {
    const float* y0     = (const float*)d_in[1];
    const int*   env    = (const int*)d_in[2];
    const float* params = (const float*)d_in[4];
    const float* domain = (const float*)d_in[5];
    float* out = (float*)d_out;
    float* tbl = (float*)d_ws;   // TBL_FLOATS*4 = 86.1 KB

    setup_tables<<<dim3(85), dim3(256), 0, stream>>>(tbl, domain);
    turb_kernel<<<dim3(4096), dim3(256), 0, stream>>>(y0, env, params, domain, tbl, out);
}

// Round 3
// 221.354 us; speedup vs baseline: 3.7018x; 2.0741x over previous
//
#include <hip/hip_runtime.h>
#include <math.h>

// Turb2dPDE via MFMA: per block b: psi = Re(IDFT2(S o DFT2(pad65(-x))))[:64,:64] then Arakawa+lap.
// 4 matmul stages on mfma_f32_16x16x32_bf16 with split-bf16 3-term products (fp32-class accuracy).
// Tables precomputed in global (bf16 hi/lo, fragment-ready layouts). j=32/c=32 terms = VALU rank-1 fixups.
// LDS 40,144 B -> 4 blocks/CU.

typedef __attribute__((ext_vector_type(8))) short short8;
typedef __attribute__((ext_vector_type(4))) float floatx4;

#define WPI 0.09666439165562847f   // 2*pi/65

// ws layout: shorts (bf16 hi|lo along K):
#define SH_TA1 0        // [80][136]  rows 0..32: -Cf[j][m] (m=0 folds m=64); 33..65: +Sf; else 0
#define SH_TB2 10880    // [80][136]  rows 0..32: C2c[k][c] (k=0 folds k=64); 33..65: C2s; else 0
#define SH_TGR 21760    // [48][72]   rows 0..32: cos(w*j*s), j=0..31 (h|l); else 0
#define SH_TGI 25216    // [48][72]   sin
#define SH_THC 28672    // [48][72]   rows p<=32: c==0 ? inv : 2inv*cos(w*c*p), c=0..31
#define SH_THS 32128    // [48][72]   c==0 ? 0 : 2inv*sin(w*c*p)
// floats:
#define FL_GR32 17792   // [48] cos(w*32*s)      (j=32 col of G)
#define FL_GI32 17840   // [48] sin(w*32*s)
#define FL_HC32 17888   // [48] 2inv*cos(w*32*p) (c=32 col of H)
#define FL_HS32 17936   // [48] 2inv*sin(w*32*p)
#define FL_SE   17984   // [8][1089] -1/(1e-12+k2)

__device__ inline unsigned short f2bh(float v) {
    unsigned u = __builtin_bit_cast(unsigned, v);
    unsigned r = (u + 0x7FFFu + ((u >> 16) & 1u)) >> 16;
    return (unsigned short)r;
}
__device__ inline float bh2f(unsigned short h) {
    unsigned u = ((unsigned)h) << 16;
    return __builtin_bit_cast(float, u);
}

__global__ void setup_tables(float* __restrict__ ws, const float* __restrict__ domain) {
    int idx = blockIdx.x * 256 + threadIdx.x;
    unsigned short* tb = (unsigned short*)ws;
    const float w = WPI;
    const float inv = 1.0f / 4225.0f;
    if (idx < 10880) {                       // TA1
        int row = idx / 136, kc = idx - row * 136;
        int m = kc & 63;
        float v = 0.f;
        if (kc < 128 && row <= 65) {
            if (row <= 32) { int j = row; v = -cosf(w * ((j * m) % 65)); if (m == 0) v -= cosf(w * ((j * 64) % 65)); }
            else { int j = row - 33; v = sinf(w * ((j * m) % 65)); if (m == 0) v += sinf(w * ((j * 64) % 65)); }
        }
        unsigned short h = f2bh(v);
        tb[SH_TA1 + idx] = (kc < 64) ? h : ((kc < 128) ? f2bh(v - bh2f(h)) : (unsigned short)0);
    } else if (idx < 21760) {                // TB2
        int i2 = idx - 10880;
        int row = i2 / 136, kc = i2 - row * 136;
        int k = kc & 63;
        float v = 0.f;
        if (kc < 128 && row <= 65) {
            if (row <= 32) { int c = row; v = cosf(w * ((k * c) % 65)); if (k == 0) v += cosf(w * ((64 * c) % 65)); }
            else { int c = row - 33; v = sinf(w * ((k * c) % 65)); if (k == 0) v += sinf(w * ((64 * c) % 65)); }
        }
        unsigned short h = f2bh(v);
        tb[SH_TB2 + i2] = (kc < 64) ? h : ((kc < 128) ? f2bh(v - bh2f(h)) : (unsigned short)0);
    } else if (idx < 25216) {                // TGr
        int i2 = idx - 21760;
        int row = i2 / 72, jc = i2 - row * 72;
        int j = jc & 31;
        float v = 0.f;
        if (jc < 64 && row <= 32) v = cosf(w * ((j * row) % 65));
        unsigned short h = f2bh(v);
        tb[SH_TGR + i2] = (jc < 32) ? h : ((jc < 64) ? f2bh(v - bh2f(h)) : (unsigned short)0);
    } else if (idx < 28672) {                // TGi
        int i2 = idx - 25216;
        int row = i2 / 72, jc = i2 - row * 72;
        int j = jc & 31;
        float v = 0.f;
        if (jc < 64 && row <= 32) v = sinf(w * ((j * row) % 65));
        unsigned short h = f2bh(v);
        tb[SH_TGI + i2] = (jc < 32) ? h : ((jc < 64) ? f2bh(v - bh2f(h)) : (unsigned short)0);
    } else if (idx < 32128) {                // THc
        int i2 = idx - 28672;
        int row = i2 / 72, cc2 = i2 - row * 72;
        int c = cc2 & 31;
        float v = 0.f;
        if (cc2 < 64 && row <= 32) v = (c == 0) ? inv : 2.f * inv * cosf(w * ((c * row) % 65));
        unsigned short h = f2bh(v);
        tb[SH_THC + i2] = (cc2 < 32) ? h : ((cc2 < 64) ? f2bh(v - bh2f(h)) : (unsigned short)0);
    } else if (idx < 35584) {                // THs
        int i2 = idx - 32128;
        int row = i2 / 72, cc2 = i2 - row * 72;
        int c = cc2 & 31;
        float v = 0.f;
        if (cc2 < 64 && row <= 32) v = (c == 0) ? 0.f : 2.f * inv * sinf(w * ((c * row) % 65));
        unsigned short h = f2bh(v);
        tb[SH_THS + i2] = (cc2 < 32) ? h : ((cc2 < 64) ? f2bh(v - bh2f(h)) : (unsigned short)0);
    } else if (idx < 35776) {                // aux fp32: Gr32,Gi32,Hc32,Hs32
        int i2 = idx - 35584;
        int grp = i2 / 48, s = i2 - grp * 48;
        float v = 0.f;
        if (s <= 32) {
            int t = (32 * s) % 65;
            if (grp == 0) v = cosf(w * t);
            else if (grp == 1) v = sinf(w * t);
            else if (grp == 2) v = 2.f * inv * cosf(w * t);
            else v = 2.f * inv * sinf(w * t);
        }
        ws[FL_GR32 + i2] = v;
    } else if (idx < 44488) {                // Se
        int i2 = idx - 35776;
        int e2 = i2 / 1089, rem = i2 - e2 * 1089;
        int a = rem / 33, b2 = rem - a * 33;
        const float DX0 = 0.04908738521234052f;
        float fdx = domain[e2] * DX0;
        float tt = 6.283185307179586f / (65.0f * fdx);
        float s2v = tt * tt;
        ws[FL_SE + i2] = -1.0f / (1e-12f + s2v * (float)(a * a + b2 * b2));
    }
}

#define MFMA(A, B, C) __builtin_amdgcn_mfma_f32_16x16x32_bf16((A), (B), (C), 0, 0, 0)

__global__ __launch_bounds__(256, 4)
void turb_kernel(const float* __restrict__ y0, const int* __restrict__ env,
                 const float* __restrict__ params, const float* __restrict__ domain,
                 const float* __restrict__ ws, float* __restrict__ out) {
    // LDS overlays (bytes):
    //  chainB @0     : PQ bf16 [66][136] (s1->s2)  THEN  XXr[64][72]@0, XXi@9216, X32 f32[2][64]@18432
    //  chainA @18944 : XB bf16 [64][136] (pre->s1) THEN streams s0..3 [33][72] (+sid*4752), S32 f32[4][33]@+19008
    //                  THEN psi f32 [64][65] @+0
    //  pad to 40144 (absorbs read-overrun of padded M/N tiles)
    __shared__ __align__(16) char lds_raw[40144];
    unsigned short* PQ  = (unsigned short*)(lds_raw);
    unsigned short* XXr = (unsigned short*)(lds_raw);
    unsigned short* XXi = (unsigned short*)(lds_raw + 9216);
    float*          X32 = (float*)(lds_raw + 18432);
    unsigned short* XB  = (unsigned short*)(lds_raw + 18944);
    unsigned short* ST  = (unsigned short*)(lds_raw + 18944);
    float*          S32 = (float*)(lds_raw + 18944 + 19008);
    float*          psi = (float*)(lds_raw + 18944);

    const int b = blockIdx.x, tid = threadIdx.x;
    const int wid = tid >> 6, lane = tid & 63;
    const int q = lane >> 4, n16 = lane & 15;
    const int e = env[b];
    const unsigned short* tb = (const unsigned short*)ws;
    const float* tf = ws;

    // ---- preamble: load x, split to bf16 hi/lo, store XB[c][r(h)|64+r(l)]
    const float* x0 = y0 + (size_t)b * 4096;
    const float4* xv4 = (const float4*)x0;
    #pragma unroll
    for (int t = 0; t < 4; t++) {
        int f = tid + 256 * t;
        float4 v = xv4[f];
        int r = f >> 4;
        int c0 = (f & 15) << 2;
        float vv[4] = {v.x, v.y, v.z, v.w};
        #pragma unroll
        for (int u = 0; u < 4; u++) {
            unsigned short h = f2bh(vv[u]);
            XB[(c0 + u) * 136 + r] = h;
            XB[(c0 + u) * 136 + 64 + r] = f2bh(vv[u] - bh2f(h));
        }
    }
    __syncthreads();

    // ---- stage1: PQ[j'][k] = [ -Cf ; Sf ] * x   (M=66->80, N=64, K=64)
    for (int pos = wid; pos < 20; pos += 4) {
        int mi = pos >> 2, ni = pos & 3;
        floatx4 acc = {0.f, 0.f, 0.f, 0.f};
        const unsigned short* Ar = tb + SH_TA1 + (16 * mi + n16) * 136 + 8 * q;
        const unsigned short* Br = XB + (16 * ni + n16) * 136 + 8 * q;
        #pragma unroll
        for (int kc = 0; kc < 64; kc += 32) {
            short8 Ah = *(const short8*)(Ar + kc);
            short8 Al = *(const short8*)(Ar + kc + 64);
            short8 Bh = *(const short8*)(Br + kc);
            short8 Bl = *(const short8*)(Br + kc + 64);
            acc = MFMA(Ah, Bh, acc);
            acc = MFMA(Ah, Bl, acc);
            acc = MFMA(Al, Bh, acc);
        }
        int col = 16 * ni + n16;
        #pragma unroll
        for (int i = 0; i < 4; i++) {
            int jp = 16 * mi + 4 * q + i;
            if (jp <= 65) {
                float v = acc[i];
                unsigned short h = f2bh(v);
                PQ[jp * 136 + col] = h;
                PQ[jp * 136 + 64 + col] = f2bh(v - bh2f(h));
            }
        }
    }
    __syncthreads();

    // ---- stage2: [A C; B D] = PQ * [C2c | C2s]  (M=66->80, N=66->80, K=64), scale by S -> streams
    const float* Se = tf + FL_SE + e * 1089;
    for (int pos = wid; pos < 25; pos += 4) {
        int mi = pos / 5, ni = pos - 5 * mi;
        floatx4 acc = {0.f, 0.f, 0.f, 0.f};
        const unsigned short* Ar = PQ + (16 * mi + n16) * 136 + 8 * q;
        const unsigned short* Br = tb + SH_TB2 + (16 * ni + n16) * 136 + 8 * q;
        #pragma unroll
        for (int kc = 0; kc < 64; kc += 32) {
            short8 Ah = *(const short8*)(Ar + kc);
            short8 Al = *(const short8*)(Ar + kc + 64);
            short8 Bh = *(const short8*)(Br + kc);
            short8 Bl = *(const short8*)(Br + kc + 64);
            acc = MFMA(Ah, Bh, acc);
            acc = MFMA(Ah, Bl, acc);
            acc = MFMA(Al, Bh, acc);
        }
        int cp = 16 * ni + n16;
        if (cp <= 65) {
            int cc = (cp <= 32) ? cp : cp - 33;
            int isS = cp >= 33;
            #pragma unroll
            for (int i = 0; i < 4; i++) {
                int jp = 16 * mi + 4 * q + i;
                if (jp <= 65) {
                    int jj = (jp <= 32) ? jp : jp - 33;
                    int isQ = jp >= 33;
                    float S = Se[cc * 33 + jj];
                    float v = acc[i] * 2.0f * S;
                    int sid = isQ ? (isS ? 3 : 1) : (isS ? 2 : 0);
                    if (sid == 2) v = -v;   // umi = -2SC
                    if (jj <= 31) {
                        unsigned short* sb = ST + sid * 2376;
                        unsigned short h = f2bh(v);
                        sb[cc * 72 + jj] = h;
                        sb[cc * 72 + 32 + jj] = f2bh(v - bh2f(h));
                    } else {
                        S32[sid * 33 + cc] = v;   // j = 32 column, fp32
                    }
                }
            }
        }
    }
    __syncthreads();
    // j=0 fixup: upr0=umr0=S(A+D), upi0=umi0=S(B-C); (0,0)->0
    if (tid < 33) {
        int c = tid;
        float v0[4];
        #pragma unroll
        for (int sid = 0; sid < 4; sid++) {
            unsigned short* sb = ST + sid * 2376;
            v0[sid] = bh2f(sb[c * 72]) + bh2f(sb[c * 72 + 32]);
        }
        float pr = 0.5f * (v0[0] + v0[3]);
        float pi2 = 0.5f * (v0[1] + v0[2]);
        if (c == 0) { pr = 0.f; pi2 = 0.f; }
        float outs[4] = {pr, pi2, pi2, pr};
        #pragma unroll
        for (int sid = 0; sid < 4; sid++) {
            unsigned short* sb = ST + sid * 2376;
            unsigned short h = f2bh(outs[sid]);
            sb[c * 72] = h;
            sb[c * 72 + 32] = f2bh(outs[sid] - bh2f(h));
        }
    }
    __syncthreads();

    // ---- stage4a: a=Gr*upr, b=Gi*upi, c=Gr*umi, d=Gi*umr (M=33->48, N=33->48, K=32 + j=32 fixup)
    for (int pos = wid; pos < 9; pos += 4) {
        int si = pos / 3, ci = pos - 3 * si;
        floatx4 aA = {0.f,0.f,0.f,0.f}, aB = aA, aC = aA, aD = aA;
        const unsigned short* GrR = tb + SH_TGR + (16 * si + n16) * 72 + 8 * q;
        const unsigned short* GiR = tb + SH_TGI + (16 * si + n16) * 72 + 8 * q;
        int brow = (16 * ci + n16) * 72 + 8 * q;
        short8 GrH = *(const short8*)(GrR);
        short8 GrL = *(const short8*)(GrR + 32);
        short8 GiH = *(const short8*)(GiR);
        short8 GiL = *(const short8*)(GiR + 32);
        const unsigned short* s0R = ST + 0 * 2376 + brow;
        const unsigned short* s1R = ST + 1 * 2376 + brow;
        const unsigned short* s2R = ST + 2 * 2376 + brow;
        const unsigned short* s3R = ST + 3 * 2376 + brow;
        short8 B0H = *(const short8*)(s0R), B0L = *(const short8*)(s0R + 32);
        short8 B1H = *(const short8*)(s1R), B1L = *(const short8*)(s1R + 32);
        short8 B2H = *(const short8*)(s2R), B2L = *(const short8*)(s2R + 32);
        short8 B3H = *(const short8*)(s3R), B3L = *(const short8*)(s3R + 32);
        aA = MFMA(GrH, B0H, aA); aA = MFMA(GrH, B0L, aA); aA = MFMA(GrL, B0H, aA);
        aB = MFMA(GiH, B1H, aB); aB = MFMA(GiH, B1L, aB); aB = MFMA(GiL, B1H, aB);
        aC = MFMA(GrH, B2H, aC); aC = MFMA(GrH, B2L, aC); aC = MFMA(GrL, B2H, aC);
        aD = MFMA(GiH, B3H, aD); aD = MFMA(GiH, B3L, aD); aD = MFMA(GiL, B3H, aD);
        int c = 16 * ci + n16;
        float u0 = S32[0 * 33 + c], u1 = S32[1 * 33 + c], u2 = S32[2 * 33 + c], u3 = S32[3 * 33 + c];
        #pragma unroll
        for (int i = 0; i < 4; i++) {
            int s = 16 * si + 4 * q + i;
            float ga = tf[FL_GR32 + s], gi2 = tf[FL_GI32 + s];
            float av = aA[i] + ga * u0;
            float bv = aB[i] + gi2 * u1;
            float cv = aC[i] + ga * u2;
            float dv = aD[i] + gi2 * u3;
            if (s <= 32 && c <= 32) {
                float xr = av - bv, xi = cv + dv;
                if (c <= 31) {
                    unsigned short h = f2bh(xr);
                    XXr[s * 72 + c] = h; XXr[s * 72 + 32 + c] = f2bh(xr - bh2f(h));
                    h = f2bh(xi);
                    XXi[s * 72 + c] = h; XXi[s * 72 + 32 + c] = f2bh(xi - bh2f(h));
                } else { X32[s] = xr; X32[64 + s] = xi; }
                if (s >= 2) {
                    int rm = 65 - s;
                    float xr2 = av + bv, xi2 = cv - dv;
                    if (c <= 31) {
                        unsigned short h = f2bh(xr2);
                        XXr[rm * 72 + c] = h; XXr[rm * 72 + 32 + c] = f2bh(xr2 - bh2f(h));
                        h = f2bh(xi2);
                        XXi[rm * 72 + c] = h; XXi[rm * 72 + 32 + c] = f2bh(xi2 - bh2f(h));
                    } else { X32[rm] = xr2; X32[64 + rm] = xi2; }
                }
            }
        }
    }
    __syncthreads();

    // ---- stage4b: E = Xr*Hc^T, F = Xi*Hs^T (M=64, N=33->48, K=32 + c=32 fixup); psi = E-F / E+F
    for (int pos = wid; pos < 12; pos += 4) {
        int ri = pos / 3, pti = pos - 3 * ri;
        floatx4 aE = {0.f,0.f,0.f,0.f}, aF = aE;
        const unsigned short* Xr1 = XXr + (16 * ri + n16) * 72 + 8 * q;
        const unsigned short* Xi1 = XXi + (16 * ri + n16) * 72 + 8 * q;
        const unsigned short* Hc1 = tb + SH_THC + (16 * pti + n16) * 72 + 8 * q;
        const unsigned short* Hs1 = tb + SH_THS + (16 * pti + n16) * 72 + 8 * q;
        short8 XrH = *(const short8*)(Xr1), XrL = *(const short8*)(Xr1 + 32);
        short8 XiH = *(const short8*)(Xi1), XiL = *(const short8*)(Xi1 + 32);
        short8 HcH = *(const short8*)(Hc1), HcL = *(const short8*)(Hc1 + 32);
        short8 HsH = *(const short8*)(Hs1), HsL = *(const short8*)(Hs1 + 32);
        aE = MFMA(XrH, HcH, aE); aE = MFMA(XrH, HcL, aE); aE = MFMA(XrL, HcH, aE);
        aF = MFMA(XiH, HsH, aF); aF = MFMA(XiH, HsL, aF); aF = MFMA(XiL, HsH, aF);
        int p = 16 * pti + n16;
        float hc32 = tf[FL_HC32 + p], hs32 = tf[FL_HS32 + p];
        #pragma unroll
        for (int i = 0; i < 4; i++) {
            int r = 16 * ri + 4 * q + i;
            float E = aE[i] + X32[r] * hc32;
            float F = aF[i] + X32[64 + r] * hs32;
            if (p <= 32) {
                psi[r * 65 + p] = E - F;
                if (p >= 2) psi[r * 65 + 65 - p] = E + F;
            }
        }
    }
    __syncthreads();

    // ---- stencil: lane=c, rows 16*wid..+15; x from global (L1/L2-hot), psi from LDS
    {
        const int c = lane;
        const int cm1 = (c + 63) & 63, cp1 = (c + 1) & 63;
        const float mu = params[2 * e];
        const float DX0 = 0.04908738521234052f;
        const float fdx = domain[e] * DX0;
        const float fdx2 = fdx * fdx;
        const float inv12 = 1.0f / (12.0f * fdx2);
        const float invf = mu / fdx2;
        float* o = out + (size_t)b * 4096;
        const int r0 = wid * 16;
        int rm = (r0 + 63) & 63;
        float xLm = x0[rm * 64 + cm1], xCm = x0[rm * 64 + c], xRm = x0[rm * 64 + cp1];
        float pLm = psi[rm * 65 + cm1], pCm = psi[rm * 65 + c], pRm = psi[rm * 65 + cp1];
        float xLc = x0[r0 * 64 + cm1], xCc = x0[r0 * 64 + c], xRc = x0[r0 * 64 + cp1];
        float pLc = psi[r0 * 65 + cm1], pCc = psi[r0 * 65 + c], pRc = psi[r0 * 65 + cp1];
        #pragma unroll
        for (int it = 0; it < 16; it++) {
            int r = r0 + it;
            int rn = (r + 1) & 63;
            float xLp = x0[rn * 64 + cm1], xCp = x0[rn * 64 + c], xRp = x0[rn * 64 + cp1];
            float pLp = psi[rn * 65 + cm1], pCp = psi[rn * 65 + c], pRp = psi[rn * 65 + cp1];
            float J1 = (pCp - pCm) * (xRc - xLc) - (pRc - pLc) * (xCp - xCm);
            float J2 = xRc * (pRp - pRm) - xLc * (pLp - pLm) - xCp * (pRp - pLp) + xCm * (pRm - pLm);
            float J3 = xRp * (pCp - pRc) - xLm * (pLc - pCm) - xLp * (pCp - pLc) + xRm * (pRc - pCm);
            float lap = xCm + xLc - 4.f * xCc + xRc + xLp + xCp;
            o[r * 64 + c] = -(J1 + J2 + J3) * inv12 + lap * invf;
            xLm = xLc; xCm = xCc; xRm = xRc; pLm = pLc; pCm = pCc; pRm = pRc;
            xLc = xLp; xCc = xCp; xRc = xRp; pLc = pLp; pCc = pCp; pRc = pRp;
        }
    }
}

extern "C" void kernel_launch(void* const* d_in, const int* in_sizes, int n_in,
                              void* d_out, int out_size, void* d_ws, size_t ws_size,
                              hipStream_t stream) {
    const float* y0     = (const float*)d_in[1];
    const int*   env    = (const int*)d_in[2];
    const float* params = (const float*)d_in[4];
    const float* domain = (const float*)d_in[5];
    float* out = (float*)d_out;
    float* ws  = (float*)d_ws;   // 106,784 B used

    setup_tables<<<dim3(174), dim3(256), 0, stream>>>(ws, domain);
    turb_kernel<<<dim3(4096), dim3(256), 0, stream>>>(y0, env, params, domain, ws, out);
}

// Round 4
// 182.488 us; speedup vs baseline: 4.4902x; 1.2130x over previous
//
#include <hip/hip_runtime.h>
#include <math.h>

// Turb2dPDE, MFMA fp16-split pipeline. Per block b:
//   Y = x * C2        (col-DFT first: x rows feed A-frags straight from global)
//   Out = F1 * Y      (row-DFT; row-reordered tables so j=32/c=32 land in fixup slots)
//   X = streams x G   (Hermitian-halved inverse, c-major)
//   psiT = Hc x X     (transposed psi; stencil reads are bank-free)
// All inter-stage LDS layouts are exactly the next stage's fragment layout ->
// every epilogue store is a contiguous half4 (b64); all LDS strides 2-way-bank (free).
// Static tables stored wave-linear in global (1KB contiguous per wave b128 load).

typedef _Float16 half8 __attribute__((ext_vector_type(8)));
typedef _Float16 half4 __attribute__((ext_vector_type(4)));
typedef float floatx4 __attribute__((ext_vector_type(4)));

#define WPI 0.09666439165562847f   // 2*pi/65

// half-unit offsets in ws
#define H_TB1 0        // [20 chunks][512] S1-B: rows [cos c0..31 | sin c0..31 | cos32,sin32], fold k=0
#define H_TA2 10240    // [20 chunks][512] S2-A: rows [-cos j0..31 | sin j0..31 | -cos32,sin32], fold m=0
#define H_TG  20480    // [12 chunks][512] S4a-B: Gr/Gi [s][j], s>32 -> 0
#define H_TH  26624    // [12 chunks][512] S4b-A: Hc/Hs [p][c], incl 1/4225 & x2(c>=1), p>32 -> 0
// float-unit offsets
#define F_GR32 16384   // [48] cos(w*32*s)
#define F_GI32 16432   // [48] sin(w*32*s)
#define F_HC32 16480   // [48] 2inv*cos(w*32*p)
#define F_HS32 16528   // [48] 2inv*sin(w*32*p)
#define F_SE   16576   // [8][1089]

__device__ __forceinline__ float trig65(int t, int isSin) {
    return isSin ? sinf(WPI * (float)t) : cosf(WPI * (float)t);
}

__global__ void setup_tables(float* __restrict__ ws, const float* __restrict__ domain) {
    int idx = blockIdx.x * 256 + threadIdx.x;
    _Float16* tbH = (_Float16*)ws;
    const float inv = 1.0f / 4225.0f;
    if (idx < 32768) {
        float v = 0.0f;
        int part;
        if (idx < 10240) {                  // TB1 (B-layout): chunk=(ni*2+kc)*2+part
            int chunk = idx >> 9, within = idx & 511;
            part = chunk & 1; int kc = (chunk >> 1) & 1, ni = chunk >> 2;
            int l2 = within >> 3, j = within & 7;
            int row = 16 * ni + (l2 & 15);
            int k = 32 * kc + 8 * (l2 >> 4) + j;
            if (row < 66) {
                int c = (row < 32) ? row : (row < 64 ? row - 32 : 32);
                int isS = (row < 32) ? 0 : (row < 64 ? 1 : row - 64);
                v = trig65((k * c) % 65, isS);
                if (k == 0) v += trig65((64 * c) % 65, isS);
            }
        } else if (idx < 20480) {           // TA2 (A-layout): chunk=(mi*2+kc)*2+part
            int i2 = idx - 10240;
            int chunk = i2 >> 9, within = i2 & 511;
            part = chunk & 1; int kc = (chunk >> 1) & 1, mi = chunk >> 2;
            int l2 = within >> 3, j = within & 7;
            int row = 16 * mi + (l2 & 15);
            int m = 32 * kc + 8 * (l2 >> 4) + j;
            if (row < 66) {
                int jr = (row < 32) ? row : (row < 64 ? row - 32 : 32);
                int isS = (row < 32) ? 0 : (row < 64 ? 1 : row - 64);
                float s = isS ? 1.0f : -1.0f;   // P rows = -cos, Q rows = +sin
                v = s * trig65((jr * m) % 65, isS);
                if (m == 0) v += s * trig65((jr * 64) % 65, isS);
            }
        } else if (idx < 26624) {           // TG: chunk=(si*2+g)*2+part
            int i2 = idx - 20480;
            int chunk = i2 >> 9, within = i2 & 511;
            part = chunk & 1; int g = (chunk >> 1) & 1, si = chunk >> 2;
            int l2 = within >> 3, j = within & 7;
            int s = 16 * si + (l2 & 15);
            int jj = 8 * (l2 >> 4) + j;
            if (s <= 32) v = trig65((s * jj) % 65, g);
        } else {                            // TH: chunk=(pi*2+h)*2+part
            int i2 = idx - 26624;
            int chunk = i2 >> 9, within = i2 & 511;
            part = chunk & 1; int h = (chunk >> 1) & 1, pi2 = chunk >> 2;
            int l2 = within >> 3, j = within & 7;
            int p = 16 * pi2 + (l2 & 15);
            int c = 8 * (l2 >> 4) + j;
            if (p <= 32) {
                if (c == 0) v = h ? 0.0f : inv;
                else v = 2.0f * inv * trig65((c * p) % 65, h);
            }
        }
        _Float16 hh = (_Float16)v;
        tbH[idx] = part ? (_Float16)(v - (float)hh) : hh;
    } else if (idx < 32960) {               // fp32 aux
        int i2 = idx - 32768;
        int grp = i2 / 48, s = i2 - grp * 48;
        float v = 0.0f;
        if (s <= 32) {
            int t = (32 * s) % 65;
            float cs = cosf(WPI * t), sn = sinf(WPI * t);
            v = (grp == 0) ? cs : (grp == 1) ? sn : (grp == 2) ? 2.0f * inv * cs : 2.0f * inv * sn;
        }
        ws[F_GR32 + i2] = v;
    } else if (idx < 41672) {               // Se
        int i2 = idx - 32960;
        int e2 = i2 / 1089, rem = i2 - e2 * 1089;
        int a = rem / 33, b2 = rem - a * 33;
        const float DX0 = 0.04908738521234052f;
        float fdx = domain[e2] * DX0;
        float tt = 6.283185307179586f / (65.0f * fdx);
        float s2v = tt * tt;
        ws[F_SE + i2] = -1.0f / (1e-12f + s2v * (float)(a * a + b2 * b2));
    }
}

#define MFMA16(A, B, C) __builtin_amdgcn_mfma_f32_16x16x32_f16((A), (B), (C), 0, 0, 0)

__global__ __launch_bounds__(256, 4)
void turb_kernel(const float* __restrict__ y0, const int* __restrict__ env,
                 const float* __restrict__ params, const float* __restrict__ domain,
                 const float* __restrict__ ws, float* __restrict__ out) {
    // LDS arenas (bytes):
    //  A @0     : Yt [66][136]h (S1->S2, overread rows to 79 lands in B, harmless/discarded)
    //             then Xr[64][72]@0 Xi@9216 X32r@18432 X32i@18688 (S4a->S4b)
    //  B @18944 : ST 4x[33][72] + S32[4][33]@+19008 (S2->S4a, +overread slack)
    //             then psiT[64][65] f32 (S4b->stencil)
    __shared__ __align__(16) char lds_raw[40448];
    _Float16* Yt  = (_Float16*)lds_raw;
    _Float16* Xr  = (_Float16*)lds_raw;
    _Float16* Xi  = (_Float16*)(lds_raw + 9216);
    float*    X32r = (float*)(lds_raw + 18432);
    float*    X32i = (float*)(lds_raw + 18688);
    _Float16* ST  = (_Float16*)(lds_raw + 18944);
    float*    S32 = (float*)(lds_raw + 18944 + 19008);
    float*    psiT = (float*)(lds_raw + 18944);

    const int b = blockIdx.x, tid = threadIdx.x;
    const int wid = tid >> 6, lane = tid & 63, n16 = lane & 15, q = lane >> 4;
    const int e = env[b];
    const _Float16* tbH = (const _Float16*)ws;
    const float* tf = ws;
    const float* Se = tf + F_SE + e * 1089;
    const float* x0 = y0 + (size_t)b * 4096;

    // ---- S1: Yt[c'][m] = sum_k x[m][k]*TB1[c'][k]  (A = x from global, wid = m-tile)
    {
        half8 Ah[2], Al[2];
        const float* xrow = x0 + (16 * wid + n16) * 64 + 8 * q;
        #pragma unroll
        for (int kc = 0; kc < 2; kc++) {
            float4 v0 = *(const float4*)(xrow + 32 * kc);
            float4 v1 = *(const float4*)(xrow + 32 * kc + 4);
            float vv[8] = {v0.x, v0.y, v0.z, v0.w, v1.x, v1.y, v1.z, v1.w};
            #pragma unroll
            for (int u = 0; u < 8; u++) {
                _Float16 h = (_Float16)vv[u];
                Ah[kc][u] = h; Al[kc][u] = (_Float16)(vv[u] - (float)h);
            }
        }
        for (int ni = 0; ni < 5; ni++) {
            floatx4 acc = {0.f, 0.f, 0.f, 0.f};
            #pragma unroll
            for (int kc = 0; kc < 2; kc++) {
                half8 Bh = *(const half8*)(tbH + H_TB1 + ((ni * 2 + kc) * 2 + 0) * 512 + lane * 8);
                half8 Bl = *(const half8*)(tbH + H_TB1 + ((ni * 2 + kc) * 2 + 1) * 512 + lane * 8);
                acc = MFMA16(Ah[kc], Bh, acc);
                acc = MFMA16(Ah[kc], Bl, acc);
                acc = MFMA16(Al[kc], Bh, acc);
            }
            int cp = 16 * ni + n16;
            if (ni < 4 || n16 < 2) {
                half4 hh, ll;
                #pragma unroll
                for (int i = 0; i < 4; i++) {
                    _Float16 h = (_Float16)acc[i];
                    hh[i] = h; ll[i] = (_Float16)(acc[i] - (float)h);
                }
                *(half4*)(Yt + cp * 136 + 16 * wid + 4 * q) = hh;
                *(half4*)(Yt + cp * 136 + 64 + 16 * wid + 4 * q) = ll;
            }
        }
    }
    __syncthreads();

    // ---- S2: Out[j'][c'] = sum_m TA2[j'][m]*Yt[c'][m] -> 4 streams ST[sid][cc][jj] + S32
    for (int pos = wid; pos < 25; pos += 4) {
        int mi = pos / 5, ni = pos - 5 * mi;
        floatx4 acc = {0.f, 0.f, 0.f, 0.f};
        #pragma unroll
        for (int kc = 0; kc < 2; kc++) {
            half8 Ah = *(const half8*)(tbH + H_TA2 + ((mi * 2 + kc) * 2 + 0) * 512 + lane * 8);
            half8 Al = *(const half8*)(tbH + H_TA2 + ((mi * 2 + kc) * 2 + 1) * 512 + lane * 8);
            half8 Bh = *(const half8*)(Yt + (16 * ni + n16) * 136 + 32 * kc + 8 * q);
            half8 Bl = *(const half8*)(Yt + (16 * ni + n16) * 136 + 64 + 32 * kc + 8 * q);
            acc = MFMA16(Ah, Bh, acc);
            acc = MFMA16(Ah, Bl, acc);
            acc = MFMA16(Al, Bh, acc);
        }
        if ((ni < 4) || (n16 < 2)) {
            int cp = 16 * ni + n16;
            int cc = (ni == 4) ? 32 : (cp & 31);
            int isS = (ni == 4) ? n16 : (ni >> 1);
            if (mi < 4) {
                int isQ = mi >> 1;
                int sid = isQ ? (isS ? 3 : 1) : (isS ? 2 : 0);
                int jjb = 16 * (mi & 1) + 4 * q;
                half4 hh, ll;
                #pragma unroll
                for (int i = 0; i < 4; i++) {
                    float S = Se[cc * 33 + jjb + i];
                    float v = 2.0f * S * acc[i];
                    if (sid == 2) v = -v;
                    _Float16 h = (_Float16)v;
                    hh[i] = h; ll[i] = (_Float16)(v - (float)h);
                }
                _Float16* sb = ST + sid * 2376 + cc * 72 + jjb;
                *(half4*)sb = hh;
                *(half4*)(sb + 32) = ll;
            } else if (q == 0) {            // rows 64 (P32) / 65 (Q32) -> S32
                float S = Se[cc * 33 + 32];
                #pragma unroll
                for (int i = 0; i < 2; i++) {
                    int sid = i ? (isS ? 3 : 1) : (isS ? 2 : 0);
                    float v = 2.0f * S * acc[i];
                    if (sid == 2) v = -v;
                    S32[sid * 33 + cc] = v;
                }
            }
        }
    }
    __syncthreads();

    // ---- j=0 fixup: upr0=umr0=S(A+D)/..., (0,0)->0
    if (tid < 33) {
        int c = tid;
        float v0[4];
        #pragma unroll
        for (int sid = 0; sid < 4; sid++)
            v0[sid] = (float)ST[sid * 2376 + c * 72] + (float)ST[sid * 2376 + c * 72 + 32];
        float pr = 0.5f * (v0[0] + v0[3]), pi = 0.5f * (v0[1] + v0[2]);
        if (c == 0) { pr = 0.f; pi = 0.f; }
        float outs[4] = {pr, pi, pi, pr};
        #pragma unroll
        for (int sid = 0; sid < 4; sid++) {
            _Float16 h = (_Float16)outs[sid];
            ST[sid * 2376 + c * 72] = h;
            ST[sid * 2376 + c * 72 + 32] = (_Float16)(outs[sid] - (float)h);
        }
    }
    __syncthreads();

    // ---- S4a: X[c-rows][s-cols]: A = streams [c][j], B = G [s][j]; j=32 via S32 fixup
    for (int pos = wid; pos < 9; pos += 4) {
        int ci = pos / 3, si = pos - 3 * ci;
        int arow = (16 * ci + n16) * 72 + 8 * q;
        half8 A0h = *(const half8*)(ST + arow),           A0l = *(const half8*)(ST + arow + 32);
        half8 A1h = *(const half8*)(ST + 2376 + arow),    A1l = *(const half8*)(ST + 2376 + arow + 32);
        half8 A2h = *(const half8*)(ST + 4752 + arow),    A2l = *(const half8*)(ST + 4752 + arow + 32);
        half8 A3h = *(const half8*)(ST + 7128 + arow),    A3l = *(const half8*)(ST + 7128 + arow + 32);
        half8 Grh = *(const half8*)(tbH + H_TG + ((si * 2 + 0) * 2 + 0) * 512 + lane * 8);
        half8 Grl = *(const half8*)(tbH + H_TG + ((si * 2 + 0) * 2 + 1) * 512 + lane * 8);
        half8 Gih = *(const half8*)(tbH + H_TG + ((si * 2 + 1) * 2 + 0) * 512 + lane * 8);
        half8 Gil = *(const half8*)(tbH + H_TG + ((si * 2 + 1) * 2 + 1) * 512 + lane * 8);
        floatx4 aA = {0.f,0.f,0.f,0.f}, aB = aA, aC = aA, aD = aA;
        aA = MFMA16(A0h, Grh, aA); aA = MFMA16(A0h, Grl, aA); aA = MFMA16(A0l, Grh, aA);
        aB = MFMA16(A1h, Gih, aB); aB = MFMA16(A1h, Gil, aB); aB = MFMA16(A1l, Gih, aB);
        aC = MFMA16(A2h, Grh, aC); aC = MFMA16(A2h, Grl, aC); aC = MFMA16(A2l, Grh, aC);
        aD = MFMA16(A3h, Gih, aD); aD = MFMA16(A3h, Gil, aD); aD = MFMA16(A3l, Gih, aD);
        int s = 16 * si + n16;
        float ga = tf[F_GR32 + s], gi2 = tf[F_GI32 + s];
        bool sval = (si < 2) || (n16 == 0);     // s <= 32
        if (ci < 2) {
            half4 hP, lP, hQ, lQ, hM, lM, hN, lN;
            #pragma unroll
            for (int i = 0; i < 4; i++) {
                int c = 16 * ci + 4 * q + i;
                float u0 = S32[c], u1 = S32[33 + c], u2 = S32[66 + c], u3 = S32[99 + c];
                float av = aA[i] + ga * u0, bv = aB[i] + gi2 * u1;
                float cv = aC[i] + ga * u2, dv = aD[i] + gi2 * u3;
                float xrP = av - bv, xiP = cv + dv, xrM = av + bv, xiM = cv - dv;
                _Float16 h;
                h = (_Float16)xrP; hP[i] = h; lP[i] = (_Float16)(xrP - (float)h);
                h = (_Float16)xiP; hQ[i] = h; lQ[i] = (_Float16)(xiP - (float)h);
                h = (_Float16)xrM; hM[i] = h; lM[i] = (_Float16)(xrM - (float)h);
                h = (_Float16)xiM; hN[i] = h; lN[i] = (_Float16)(xiM - (float)h);
            }
            int cb = 16 * ci + 4 * q;
            if (sval) {
                *(half4*)(Xr + s * 72 + cb) = hP;  *(half4*)(Xr + s * 72 + 32 + cb) = lP;
                *(half4*)(Xi + s * 72 + cb) = hQ;  *(half4*)(Xi + s * 72 + 32 + cb) = lQ;
                if (s >= 2) {
                    int sm = 65 - s;
                    *(half4*)(Xr + sm * 72 + cb) = hM;  *(half4*)(Xr + sm * 72 + 32 + cb) = lM;
                    *(half4*)(Xi + sm * 72 + cb) = hN;  *(half4*)(Xi + sm * 72 + 32 + cb) = lN;
                }
            }
        } else if (q == 0 && sval) {            // c = 32 column -> fp32
            float u0 = S32[32], u1 = S32[65], u2 = S32[98], u3 = S32[131];
            float av = aA[0] + ga * u0, bv = aB[0] + gi2 * u1;
            float cv = aC[0] + ga * u2, dv = aD[0] + gi2 * u3;
            X32r[s] = av - bv; X32i[s] = cv + dv;
            if (s >= 2) { X32r[65 - s] = av + bv; X32i[65 - s] = cv - dv; }
        }
    }
    __syncthreads();

    // ---- S4b: psiT[p][r] = E-F, psiT[65-p][r] = E+F;  A = Hc/Hs, B = Xr/Xi; c=32 via X32
    for (int pos = wid; pos < 12; pos += 4) {
        int ri = pos / 3, pti = pos - 3 * ri;
        int brow = (16 * ri + n16) * 72 + 8 * q;
        half8 Brh = *(const half8*)(Xr + brow), Brl = *(const half8*)(Xr + brow + 32);
        half8 Bih = *(const half8*)(Xi + brow), Bil = *(const half8*)(Xi + brow + 32);
        half8 Hch = *(const half8*)(tbH + H_TH + ((pti * 2 + 0) * 2 + 0) * 512 + lane * 8);
        half8 Hcl = *(const half8*)(tbH + H_TH + ((pti * 2 + 0) * 2 + 1) * 512 + lane * 8);
        half8 Hsh = *(const half8*)(tbH + H_TH + ((pti * 2 + 1) * 2 + 0) * 512 + lane * 8);
        half8 Hsl = *(const half8*)(tbH + H_TH + ((pti * 2 + 1) * 2 + 1) * 512 + lane * 8);
        floatx4 aE = {0.f,0.f,0.f,0.f}, aF = aE;
        aE = MFMA16(Hch, Brh, aE); aE = MFMA16(Hch, Brl, aE); aE = MFMA16(Hcl, Brh, aE);
        aF = MFMA16(Hsh, Bih, aF); aF = MFMA16(Hsh, Bil, aF); aF = MFMA16(Hsl, Bih, aF);
        int r = 16 * ri + n16;
        float xr32 = X32r[r], xi32 = X32i[r];
        #pragma unroll
        for (int i = 0; i < 4; i++) {
            int p = 16 * pti + 4 * q + i;
            if (pti < 2 || (q == 0 && i == 0)) {
                float E = aE[i] + xr32 * tf[F_HC32 + p];
                float F = aF[i] + xi32 * tf[F_HS32 + p];
                psiT[p * 65 + r] = E - F;
                if (p >= 2) psiT[(65 - p) * 65 + r] = E + F;
            }
        }
    }
    __syncthreads();

    // ---- stencil: lane=c, rows 16*wid..+15; x from global (coalesced rows), psi from psiT
    {
        const int c = lane;
        const int cm1 = (c + 63) & 63, cp1 = (c + 1) & 63;
        const float mu = params[2 * e];
        const float DX0 = 0.04908738521234052f;
        const float fdx = domain[e] * DX0;
        const float fdx2 = fdx * fdx;
        const float inv12 = 1.0f / (12.0f * fdx2);
        const float invf = mu / fdx2;
        float* o = out + (size_t)b * 4096;
        const int r0 = wid * 16;
        int rm = (r0 + 63) & 63;
        float xLm = x0[rm * 64 + cm1], xCm = x0[rm * 64 + c], xRm = x0[rm * 64 + cp1];
        float pLm = psiT[cm1 * 65 + rm], pCm = psiT[c * 65 + rm], pRm = psiT[cp1 * 65 + rm];
        float xLc = x0[r0 * 64 + cm1], xCc = x0[r0 * 64 + c], xRc = x0[r0 * 64 + cp1];
        float pLc = psiT[cm1 * 65 + r0], pCc = psiT[c * 65 + r0], pRc = psiT[cp1 * 65 + r0];
        #pragma unroll
        for (int it = 0; it < 16; it++) {
            int r = r0 + it;
            int rn = (r + 1) & 63;
            float xLp = x0[rn * 64 + cm1], xCp = x0[rn * 64 + c], xRp = x0[rn * 64 + cp1];
            float pLp = psiT[cm1 * 65 + rn], pCp = psiT[c * 65 + rn], pRp = psiT[cp1 * 65 + rn];
            float J1 = (pCp - pCm) * (xRc - xLc) - (pRc - pLc) * (xCp - xCm);
            float J2 = xRc * (pRp - pRm) - xLc * (pLp - pLm) - xCp * (pRp - pLp) + xCm * (pRm - pLm);
            float J3 = xRp * (pCp - pRc) - xLm * (pLc - pCm) - xLp * (pCp - pLc) + xRm * (pRc - pCm);
            float lap = xCm + xLc - 4.f * xCc + xRc + xLp + xCp;
            o[r * 64 + c] = -(J1 + J2 + J3) * inv12 + lap * invf;
            xLm = xLc; xCm = xCc; xRm = xRc; pLm = pLc; pCm = pCc; pRm = pRc;
            xLc = xLp; xCc = xCp; xRc = xRp; pLc = pLp; pCc = pCp; pRc = pRp;
        }
    }
}

extern "C" void kernel_launch(void* const* d_in, const int* in_sizes, int n_in,
                              void* d_out, int out_size, void* d_ws, size_t ws_size,
                              hipStream_t stream) {
    const float* y0     = (const float*)d_in[1];
    const int*   env    = (const int*)d_in[2];
    const float* params = (const float*)d_in[4];
    const float* domain = (const float*)d_in[5];
    float* out = (float*)d_out;
    float* ws  = (float*)d_ws;   // 101,152 B used

    setup_tables<<<dim3(163), dim3(256), 0, stream>>>(ws, domain);
    turb_kernel<<<dim3(4096), dim3(256), 0, stream>>>(y0, env, params, domain, ws, out);
}